// Round 6
// baseline (536.616 us; speedup 1.0000x reference)
//
#include <hip/hip_runtime.h>
#include <math.h>

#define HDIM 256
#define NHEADS 8
#define NEG 0.2f
#define STRIDE 768   // padded CSR row stride (max degree ~590)
#define GRID 512     // persistent blocks, 1 node/block; __launch_bounds__(256,2)
#define NGRP 32      // barrier groups (16 blocks/group)

typedef float f32x4 __attribute__((ext_vector_type(4)));
typedef _Float16 f16x8 __attribute__((ext_vector_type(8)));
typedef __fp16 fp16v2 __attribute__((ext_vector_type(2)));

union H8 { f16x8 v8; fp16v2 v2[4]; _Float16 h[8]; };

#if __has_builtin(__builtin_amdgcn_fdot2)
#define FDOT2(a, b, c) __builtin_amdgcn_fdot2((a), (b), (c), false)
#else
__device__ __forceinline__ float FDOT2(fp16v2 a, fp16v2 b, float c) {
  return fmaf((float)a[1], (float)b[1], fmaf((float)a[0], (float)b[0], c));
}
#endif

// ---- write-through stores (relaxed agent atomics; cross-phase data) --------
__device__ __forceinline__ void st_u64(void* p, unsigned long long v) {
  __hip_atomic_store((unsigned long long*)p, v, __ATOMIC_RELAXED,
                     __HIP_MEMORY_SCOPE_AGENT);
}
__device__ __forceinline__ void st_f32(float* p, float v) {
  __hip_atomic_store(p, v, __ATOMIC_RELAXED, __HIP_MEMORY_SCOPE_AGENT);
}

// ---------------- zero scratch (goA + gcnt + rcnt + asum + dcol) -------------
__global__ __launch_bounds__(256) void zero_k(int* __restrict__ p) {
  p[blockIdx.x * 256 + threadIdx.x] = 0;
}

// ---------------- relaxed-only hierarchical grid barrier ---------------------
__device__ __forceinline__ void gbar(int* goA, int* gcnt, int ep) {
  __syncthreads();                       // drains vmcnt for every thread
  int t = threadIdx.x, b = blockIdx.x;
  int g = b >> 4;
  if (t == 0)
    __hip_atomic_fetch_add(&gcnt[g << 6], 1, __ATOMIC_RELAXED,
                           __HIP_MEMORY_SCOPE_AGENT);
  if (b == 0) {
    if (t < NGRP) {
      while (__hip_atomic_load(&gcnt[t << 6], __ATOMIC_RELAXED,
                               __HIP_MEMORY_SCOPE_AGENT) < ep * 16)
        __builtin_amdgcn_s_sleep(2);
    }
    __syncthreads();
    if (t < NGRP)
      __hip_atomic_store(&goA[t << 6], ep, __ATOMIC_RELAXED,
                         __HIP_MEMORY_SCOPE_AGENT);
  } else if (t == 0) {
    while (__hip_atomic_load(&goA[g << 6], __ATOMIC_RELAXED,
                             __HIP_MEMORY_SCOPE_AGENT) < ep)
      __builtin_amdgcn_s_sleep(2);
  }
  __syncthreads();
}

// ---------------- work: single-pass padded-CSR build (no self-loop slot) -----
__device__ __forceinline__ void build_work(int b, const int* ei, const float* ea,
    int E, int* rcnt, float* asum, int* dcol, float4* csr, char* SMEM) {
  int*   lcnt = (int*)SMEM;                 // 512
  float* ls0  = (float*)(SMEM + 2048);
  float* ls1  = (float*)(SMEM + 4096);
  float* ls2  = (float*)(SMEM + 6144);
  int*   lcol = (int*)(SMEM + 8192);        // 1024
  int*   lbase= (int*)(SMEM + 12288);       // 512 -> 14336 total
  int t = threadIdx.x;
  for (int n = t; n < 512; n += 256) {
    lcnt[n] = 0; ls0[n] = 0.f; ls1[n] = 0.f; ls2[n] = 0.f;
    lcol[n] = 0; lcol[512 + n] = 0;
  }
  __syncthreads();
  int e0 = b << 10, e1 = min(E, e0 + 1024);

  int nd[4], ns[4], slot[4];
  float va0[4], va1[4], va2[4];
#pragma unroll
  for (int k = 0; k < 4; ++k) {
    int e = e0 + t + (k << 8);
    if (e < e1) {
      int src = ei[e], dst = ei[E + e];
      float a0 = ea[3*e], a1 = ea[3*e+1], a2 = ea[3*e+2];
      nd[k] = dst; ns[k] = src; va0[k] = a0; va1[k] = a1; va2[k] = a2;
      slot[k] = atomicAdd(&lcnt[dst], 1);
      atomicAdd(&ls0[dst], a0);
      atomicAdd(&ls1[dst], a1);
      atomicAdd(&ls2[dst], a2);
      int idx = 0; float best = a0;
      if (a1 > best) { best = a1; idx = 1; }
      if (a2 > best) { idx = 2; }
      if (idx) {
        int o = (idx - 1) << 9;
        atomicAdd(&lcol[o + src], 1);
        atomicAdd(&lcol[o + dst], 1);
      }
    } else {
      nd[k] = -1;
    }
  }
  __syncthreads();
  for (int n = t; n < 512; n += 256) {
    int c = lcnt[n];
    if (c) {
      lbase[n] = atomicAdd(&rcnt[n], c);
      atomicAdd(&asum[n],        ls0[n]);
      atomicAdd(&asum[512 + n],  ls1[n]);
      atomicAdd(&asum[1024 + n], ls2[n]);
    }
    int c0 = lcol[n], c1 = lcol[512 + n];
    if (c0) atomicAdd(&dcol[n], c0);
    if (c1) atomicAdd(&dcol[512 + n], c1);
  }
  __syncthreads();
#pragma unroll
  for (int k = 0; k < 4; ++k) {
    if (nd[k] >= 0) {
      int pos = nd[k]*STRIDE + lbase[nd[k]] + slot[k];
      unsigned long long* p = (unsigned long long*)&csr[pos];
      union { float f[2]; unsigned long long u; } h0, h1;
      h0.f[0] = va0[k]; h0.f[1] = va1[k];
      h1.f[0] = va2[k]; h1.f[1] = __int_as_float(ns[k]);
      st_u64(p, h0.u);
      st_u64(p + 1, h1.u);
    }
  }
}

// ---------------- work: weight prep (dst-linear; Whall frag layout + W2h) ----
__device__ __forceinline__ void wprep_work(int wid, const float* Wl,
    const float* Wr, const float* p1W, const float* W2,
    unsigned short* dst, unsigned short* W2h) {
  int q = wid * 256 + (int)threadIdx.x;
  int base = q << 2;                        // 4 elements per thread
  const float* src; unsigned short* d; int k, n, stride;
  if (base < 10*65536) {
    int s = base >> 16, r = base & 65535;
    int kj = r & 7, lane = (r >> 3) & 63, c = (r >> 9) & 7, nt = r >> 12;
    src = (s < 4) ? (Wl + (size_t)s*65536)
        : (s < 8) ? (Wr + (size_t)(s-4)*65536)
                  : (p1W + (size_t)(s-8)*65536);
    k = c*32 + (lane >> 4)*8 + kj;
    n = nt*16 + (lane & 15);
    d = dst + base; stride = 256;
  } else {
    int off = base - 10*65536;
    int kj = off & 7, lane = (off >> 3) & 63, nt = (off >> 9) & 7, c = off >> 12;
    k = c*32 + (lane >> 4)*8 + kj;
    n = nt*16 + (lane & 15);
    src = W2; d = W2h + off; stride = 128;
  }
  union { fp16v2 v[2]; unsigned long long u; } uu;
  uu.v[0] = __builtin_amdgcn_cvt_pkrtz(src[(size_t)k*stride + n],
                                       src[(size_t)(k+1)*stride + n]);
  uu.v[1] = __builtin_amdgcn_cvt_pkrtz(src[(size_t)(k+2)*stride + n],
                                       src[(size_t)(k+3)*stride + n]);
  st_u64(d, uu.u);
}

// ---------------- work: rank-1 layer-0 maps  u=embW@W, v=embb@W+b ------------
__device__ __forceinline__ void embmap_work(int q, const float* Wl0,
    const float* Wr0, const float* embW, const float* embb,
    const float* bl0, const float* br0,
    float* ul, float* vl, float* ur, float* vr) {
  const float* W  = q ? Wr0 : Wl0;
  const float* bb = q ? br0 : bl0;
  float* u = q ? ur : ul;
  float* v = q ? vr : vl;
  int c = threadIdx.x;
  float su = 0.f, sv = 0.f;
  for (int k = 0; k < 256; ++k) {
    float wv = W[(size_t)k*256 + c];
    su = fmaf(embW[k], wv, su);
    sv = fmaf(embb[k], wv, sv);
  }
  st_f32(&u[c], su);
  st_f32(&v[c], sv + bb[c]);
}

// ---------------- online-softmax edge step (packed f16 scoring) --------------
__device__ __forceinline__ void edge_step(float rx, float ry, float rz,
    f16x8 cur, f16x8 xr8, const union H8& w0u, const union H8& w1u,
    const union H8& w2u, const union H8& avu,
    float& mh, float& lh, float* acc) {
  _Float16 hx = (_Float16)rx, hy = (_Float16)ry, hz = (_Float16)rz;
  f16x8 s = cur + xr8;
  s = s + w0u.v8 * hx;
  s = s + w1u.v8 * hy;
  s = s + w2u.v8 * hz;
  union H8 m;
  m.v8 = __builtin_elementwise_max(s, s * (_Float16)NEG);
  float partial = FDOT2(m.v2[3], avu.v2[3],
                  FDOT2(m.v2[2], avu.v2[2],
                  FDOT2(m.v2[1], avu.v2[1],
                  FDOT2(m.v2[0], avu.v2[0], 0.f))));
  partial += __shfl_xor(partial, 1);
  partial += __shfl_xor(partial, 2);
  if (partial - mh > 8.f) {
    float sc = __expf(mh - partial);
    lh *= sc;
#pragma unroll
    for (int j = 0; j < 8; ++j) acc[j] *= sc;
    mh = partial;
  }
  float pw = __expf(partial - mh);
  lh += pw;
  union H8 cu; cu.v8 = cur;
#pragma unroll
  for (int j = 0; j < 8; ++j) acc[j] = fmaf(pw, (float)cu.h[j], acc[j]);
}

// ---------------- work: all-pairs policy MLP via MFMA ------------------------
__device__ __forceinline__ void pair_work(int bb,
    const unsigned short* Ah, const unsigned short* Bh,
    const unsigned short* W2h, const float* b2, const float* W3,
    const float* b3, float* out, int N) {
  int half = bb & 1;
  int b = bb >> 1, ti = 0, rem = 32;
  while (b >= rem) { b -= rem; ti++; rem--; }
  int tj = ti + b;
  int i0 = ti * 16 + half * 8;
  int j0 = tj * 16;

  int t = threadIdx.x;
  int w = t >> 6, l = t & 63;
  int quad = l >> 4, nl = l & 15;

  float b2v[8], w3v[8];
#pragma unroll
  for (int nt = 0; nt < 8; ++nt) {
    b2v[nt] = b2[nt*16 + nl];
    w3v[nt] = W3[nt*16 + nl];
  }

  const unsigned short* Brow = Bh + (size_t)(j0 + nl) * HDIM;
  const unsigned short* Arow0 = Ah + (size_t)(i0 + w*2) * HDIM;
  const f16x8 zv = {};

  f32x4 acc[2][8];
#pragma unroll
  for (int a2 = 0; a2 < 2; ++a2)
#pragma unroll
    for (int nt = 0; nt < 8; ++nt) acc[a2][nt] = (f32x4){0.f,0.f,0.f,0.f};

  for (int c = 0; c < 8; ++c) {
    int kb = c*32 + quad*8;
    f16x8 bv = *(const f16x8*)(Brow + kb);

    f16x8 afrag[2];
#pragma unroll
    for (int a2 = 0; a2 < 2; ++a2) {
      f16x8 av = *(const f16x8*)(Arow0 + (size_t)a2*HDIM + kb);
      afrag[a2] = __builtin_elementwise_max(av + bv, zv);
    }

#pragma unroll
    for (int nt = 0; nt < 8; ++nt) {
      f16x8 bfrag = *(const f16x8*)(W2h + (size_t)(((c*8 + nt)*64 + l) * 8));
#pragma unroll
      for (int a2 = 0; a2 < 2; ++a2)
        acc[a2][nt] = __builtin_amdgcn_mfma_f32_16x16x32_f16(
            afrag[a2], bfrag, acc[a2][nt], 0, 0, 0);
    }
  }

  float b3v = b3[0];
#pragma unroll
  for (int a2 = 0; a2 < 2; ++a2) {
    int i = i0 + w*2 + a2;
#pragma unroll
    for (int r = 0; r < 4; ++r) {
      float s = 0.f;
#pragma unroll
      for (int nt = 0; nt < 8; ++nt)
        s = fmaf(fmaxf(acc[a2][nt][r] + b2v[nt], 0.f), w3v[nt], s);
      s += __shfl_xor(s, 1);
      s += __shfl_xor(s, 2);
      s += __shfl_xor(s, 4);
      s += __shfl_xor(s, 8);
      if (nl == 0) {
        int j = j0 + quad*4 + r;
        if (i < j)
          out[(size_t)i*(2*N - i - 1)/2 + (j - i - 1)] = s + b3v;
      }
    }
  }
}

// ---------------- work: value head solo (pool + MLP, one block) --------------
__device__ __forceinline__ void value_solo(const float* h3, const float* v1W,
    const float* v1b, const float* v2W, const float* v2b,
    float* out_val, int N, char* SMEM) {
  float* repr = (float*)SMEM;           // 512 f32
  float* wsum = (float*)(SMEM + 2048);  // 4 f32
  int t = threadIdx.x;
  float s = 0.f, m = -INFINITY;
  for (int nn = 0; nn < N; ++nn) {
    float v = h3[(size_t)nn*HDIM + t];
    s += v; m = fmaxf(m, v);
  }
  repr[t] = s / (float)N;
  repr[256 + t] = m;
  __syncthreads();
  float p = 0.f;
#pragma unroll 8
  for (int k = 0; k < 512; ++k)
    p = fmaf(repr[k], v1W[(size_t)k*HDIM + t], p);
  float a = fmaxf(p + v1b[t], 0.f);
  float pd = a * v2W[t];
#pragma unroll
  for (int off = 1; off < 64; off <<= 1) pd += __shfl_xor(pd, off);
  if ((t & 63) == 0) wsum[t >> 6] = pd;
  __syncthreads();
  if (t == 0) out_val[0] = wsum[0] + wsum[1] + wsum[2] + wsum[3] + v2b[0];
}

// ---------------- the persistent mega-kernel ---------------------------------
__global__ __launch_bounds__(256, 2) void mega(
    const float* __restrict__ x, const int* __restrict__ ei,
    const float* __restrict__ ea,
    const float* __restrict__ embW, const float* __restrict__ embb,
    const float* __restrict__ Wl, const float* __restrict__ bl,
    const float* __restrict__ Wr, const float* __restrict__ br,
    const float* __restrict__ We, const float* __restrict__ att,
    const float* __restrict__ gb, const float* __restrict__ lng,
    const float* __restrict__ lnb,
    const float* __restrict__ p1W, const float* __restrict__ p1b,
    const float* __restrict__ p2W, const float* __restrict__ p2b,
    const float* __restrict__ p3W, const float* __restrict__ p3b,
    const float* __restrict__ v1W, const float* __restrict__ v1b,
    const float* __restrict__ v2W, const float* __restrict__ v2b,
    const float* __restrict__ coup,
    int* rcnt, float* asum, int* dcol, float* epart,
    float* ul, float* vl, float* ur, float* vr,
    float4* csr, unsigned short* xlh,
    unsigned short* Abh, unsigned short* Bbh, float* h3,
    unsigned short* W2h, unsigned short* Whall,
    int* goA, int* gcnt,
    float* out, int N, int E) {
  __shared__ __align__(16) char SMEM[14336];
  float* lacc = (float*)SMEM;                       // 8192
  float* lm   = (float*)(SMEM + 8192);              // 256
  float* llv  = (float*)(SMEM + 8448);              // 256
  float* rs1  = (float*)(SMEM + 8704);              // 16
  float* rs2  = (float*)(SMEM + 8720);              // 16
  unsigned short* xl16 = (unsigned short*)(SMEM + 8736);  // 512
  unsigned short* xr16 = (unsigned short*)(SMEM + 9248);  // 512
  unsigned short* h16  = (unsigned short*)(SMEM + 9760);  // 512
  float* h32 = (float*)(SMEM + 10272);              // 1024

  size_t P = (size_t)N*(N-1)/2;
  int b = blockIdx.x, t = threadIdx.x;
  int ph = 0;

  // ---- P0: build CSR (254) + weight prep (672) + embmap (2) ----
  {
    int WB = (E + 1023) >> 10;
    int tot = WB + 672 + 2;
    for (int wid = b; wid < tot; wid += GRID) {
      if (wid < WB)            build_work(wid, ei, ea, E, rcnt, asum, dcol, csr, SMEM);
      else if (wid < WB + 672) wprep_work(wid - WB, Wl, Wr, p1W, p2W, Whall, W2h);
      else                     embmap_work(wid - WB - 672, Wl, Wr, embW, embb,
                                           bl, br, ul, vl, ur, vr);
    }
  }
  ++ph; gbar(goA, gcnt, ph);

  // ---- persistent per-thread state for node n = b ----
  int n = b;
  float h_prev = 0.f;
  int g = t >> 5, lane = t & 31, hd = lane >> 2, qd = lane & 3;
  int cb = hd*32 + qd*8;

  for (int l = 0; l < 4; ++l) {
    if (n < N) {
      // energy partials by blocks 0,1 at L0; energy final by block 0 at L1
      if (l == 0 && n < 2) {
        int id = n*256 + t;
        float e = 0.f;
        if (id < N) {
          float d1 = (float)dcol[id], d2 = (float)dcol[512 + id];
          e = d1*d1 + d2*d2;
        }
#pragma unroll
        for (int off = 1; off < 64; off <<= 1) e += __shfl_xor(e, off);
        if ((t & 63) == 0) rs1[t >> 6] = e;
        __syncthreads();
        if (t == 0) st_f32(&epart[n], rs1[0] + rs1[1] + rs1[2] + rs1[3]);
        __syncthreads();
      }
      if (l == 1 && n == 0 && t == 0) {
        float e0 = epart[0], e1 = epart[1];
        out[P + 1] = coup[0] * (e0 + e1) / (2.f * (float)N);
      }

      // -- entry: xl16/xr16 for this layer --
      if (l == 0) {
        float xv = x[n];
        float xl0 = fmaf(xv, ul[t], vl[t]);
        float xr0 = fmaf(xv, ur[t], vr[t]);
        _Float16 ha = (_Float16)xl0, hb = (_Float16)xr0;
        xl16[t] = *(unsigned short*)&ha;
        xr16[t] = *(unsigned short*)&hb;
        h_prev = fmaf(xv, embW[t], embb[t]);
      }
      __syncthreads();

      // -- gather setup --
      const float* Wel = We + (size_t)l*3*HDIM;
      const float* atl = att + (size_t)l*HDIM;
      union H8 w0u, w1u, w2u, avu;
#pragma unroll
      for (int p = 0; p < 4; ++p) {
        w0u.v2[p] = __builtin_amdgcn_cvt_pkrtz(Wel[cb+2*p],          Wel[cb+2*p+1]);
        w1u.v2[p] = __builtin_amdgcn_cvt_pkrtz(Wel[HDIM+cb+2*p],     Wel[HDIM+cb+2*p+1]);
        w2u.v2[p] = __builtin_amdgcn_cvt_pkrtz(Wel[2*HDIM+cb+2*p],   Wel[2*HDIM+cb+2*p+1]);
        avu.v2[p] = __builtin_amdgcn_cvt_pkrtz(atl[cb+2*p],          atl[cb+2*p+1]);
      }
      f16x8 xr8 = *(const f16x8*)(xr16 + cb);
      f16x8 xl8self = *(const f16x8*)(xl16 + cb);

      int cnt = rcnt[n];
      int base = n * STRIDE;
      int send = base + cnt;
      float mh = -INFINITY, lh = 0.f;
      float acc[8] = {0.f,0.f,0.f,0.f,0.f,0.f,0.f,0.f};

      if (g == 0) {                       // self-loop seed (mean edge_attr)
        float inv = 1.f / fmaxf((float)cnt, 1.f);
        edge_step(asum[n]*inv, asum[512+n]*inv, asum[1024+n]*inv,
                  xl8self, xr8, w0u, w1u, w2u, avu, mh, lh, acc);
      }

      if (l == 0) {
        // neighbor xl computed on the fly: xl0[src] = x[src]*ul + vl
        float ul8[8], vl8[8];
#pragma unroll
        for (int j = 0; j < 8; ++j) { ul8[j] = ul[cb+j]; vl8[j] = vl[cb+j]; }
        int idx = base + g;
        if (idx < send) {
          int i1 = idx + 8, i2 = idx + 16;
          float4 rec  = csr[idx];
          float4 rec1 = csr[i1 < send ? i1 : base];
          float4 rec2 = csr[i2 < send ? i2 : base];
          float xs  = x[__float_as_int(rec.w)];
          float xs1 = x[__float_as_int(rec1.w)];
          while (idx < send) {
            int i3 = i2 + 8;
            float4 rec3 = csr[i3 < send ? i3 : base];
            float xs2 = x[__float_as_int(rec2.w)];
            union H8 cur;
#pragma unroll
            for (int p = 0; p < 4; ++p)
              cur.v2[p] = __builtin_amdgcn_cvt_pkrtz(
                  fmaf(xs, ul8[2*p], vl8[2*p]),
                  fmaf(xs, ul8[2*p+1], vl8[2*p+1]));
            edge_step(rec.x, rec.y, rec.z, cur.v8, xr8, w0u, w1u, w2u, avu,
                      mh, lh, acc);
            rec = rec1; rec1 = rec2; rec2 = rec3;
            xs = xs1; xs1 = xs2;
            idx = i1; i1 = i2; i2 = i3;
          }
        }
      } else {
        const unsigned short* xg = xlh + (size_t)(l-1)*N*HDIM;
        int idx = base + g;
        if (idx < send) {
          int i1 = idx + 8, i2 = idx + 16;
          float4 rec  = csr[idx];
          float4 rec1 = csr[i1 < send ? i1 : base];
          float4 rec2 = csr[i2 < send ? i2 : base];
          union H8 cur, nxt, nx2;
          cur.v8 = *(const f16x8*)(xg + (size_t)__float_as_int(rec.w)*HDIM + cb);
          nxt.v8 = *(const f16x8*)(xg + (size_t)__float_as_int(rec1.w)*HDIM + cb);
          while (idx < send) {
            int i3 = i2 + 8;
            float4 rec3 = csr[i3 < send ? i3 : base];
            nx2.v8 = *(const f16x8*)(xg +
                      (size_t)__float_as_int(rec2.w)*HDIM + cb);
            edge_step(rec.x, rec.y, rec.z, cur.v8, xr8, w0u, w1u, w2u, avu,
                      mh, lh, acc);
            rec = rec1; rec1 = rec2; rec2 = rec3;
            cur.v8 = nxt.v8; nxt.v8 = nx2.v8;
            idx = i1; i1 = i2; i2 = i3;
          }
        }
      }

      // -- merge 8 group-partials --
#pragma unroll
      for (int j = 0; j < 8; ++j) lacc[g*HDIM + cb + j] = acc[j];
      if (qd == 0) { lm[g*NHEADS + hd] = mh; llv[g*NHEADS + hd] = lh; }
      __syncthreads();

      int c = t, hh = c >> 5;
      float M = -INFINITY;
#pragma unroll
      for (int g2 = 0; g2 < 8; ++g2) M = fmaxf(M, lm[g2*NHEADS + hh]);
      float L = 0.f, o = 0.f;
#pragma unroll
      for (int g2 = 0; g2 < 8; ++g2) {
        float e2 = __expf(lm[g2*NHEADS + hh] - M);
        L = fmaf(llv[g2*NHEADS + hh], e2, L);
        o = fmaf(lacc[g2*HDIM + c], e2, o);
      }
      float val = o / L + gb[l*HDIM + c] + h_prev;

      // -- LayerNorm + relu --
      float vs = val, vq = val * val;
#pragma unroll
      for (int off = 1; off < 64; off <<= 1) {
        vs += __shfl_xor(vs, off);
        vq += __shfl_xor(vq, off);
      }
      if ((t & 63) == 0) { rs1[t >> 6] = vs; rs2[t >> 6] = vq; }
      __syncthreads();
      float S1 = rs1[0] + rs1[1] + rs1[2] + rs1[3];
      float S2 = rs2[0] + rs2[1] + rs2[2] + rs2[3];
      float mu = S1 * (1.f/HDIM);
      float var = S2 * (1.f/HDIM) - mu * mu;
      float y = (val - mu) * rsqrtf(var + 1e-5f);
      y = fmaf(y, lng[l*HDIM + c], lnb[l*HDIM + c]);
      float h_new = fmaxf(y, 0.f);
      h_prev = h_new;
      h32[t] = h_new;
      _Float16 hh16 = (_Float16)h_new;
      h16[t] = *(unsigned short*)&hh16;
      __syncthreads();                    // h16 ready; xl16/xr16 reads done

      // -- fused next-op GEMM (FDOT2 vs Whall fragment layout) --
      const unsigned short* WhA;
      const unsigned short* WhB;
      const float* bA;
      const float* bB;
      if (l < 3) {
        WhA = Whall + (size_t)(l+1)*65536;
        WhB = Whall + (size_t)(4+l+1)*65536;
        bA = bl + (l+1)*HDIM; bB = br + (l+1)*HDIM;
      } else {
        WhA = Whall + (size_t)8*65536;
        WhB = Whall + (size_t)9*65536;
        bA = p1b; bB = nullptr;
      }
      int nt = t >> 4, nl = t & 15;
      const fp16v2* h2 = (const fp16v2*)h16;
      float accA = 0.f, accB = 0.f;
#pragma unroll
      for (int ccc = 0; ccc < 8; ++ccc) {
#pragma unroll
        for (int q = 0; q < 4; ++q) {
          size_t fo = (size_t)(nt*8 + ccc)*512 + (q*16 + nl)*8;
          union H8 wa, wb;
          wa.v8 = *(const f16x8*)(WhA + fo);
          wb.v8 = *(const f16x8*)(WhB + fo);
          int hb2 = ccc*16 + q*4;
#pragma unroll
          for (int p = 0; p < 4; ++p) {
            accA = FDOT2(wa.v2[p], h2[hb2 + p], accA);
            accB = FDOT2(wb.v2[p], h2[hb2 + p], accB);
          }
        }
      }
      float xlv = accA + bA[t];
      float xrv = accB + (bB ? bB[t] : 0.f);
      _Float16 ga16 = (_Float16)xlv, gb16 = (_Float16)xrv;
      xl16[t] = *(unsigned short*)&ga16;
      xr16[t] = *(unsigned short*)&gb16;
      __syncthreads();

      // -- write-through outputs --
      if (l < 3) {
        if (t < 64) {
          unsigned long long* dst =
              (unsigned long long*)(xlh + (size_t)l*N*HDIM + (size_t)n*HDIM);
          st_u64(&dst[t], ((const unsigned long long*)xl16)[t]);
        }
      } else {
        if (t < 64) {
          unsigned long long* dst =
              (unsigned long long*)(Abh + (size_t)n*HDIM);
          st_u64(&dst[t], ((const unsigned long long*)xl16)[t]);
        } else if (t < 128) {
          unsigned long long* dst =
              (unsigned long long*)(Bbh + (size_t)n*HDIM);
          st_u64(&dst[t-64], ((const unsigned long long*)xr16)[t-64]);
        } else {
          unsigned long long* dst =
              (unsigned long long*)(h3 + (size_t)n*HDIM);
          st_u64(&dst[t-128], ((const unsigned long long*)h32)[t-128]);
        }
      }
    }
    ++ph; gbar(goA, gcnt, ph);
  }

  // ---- FINAL: block 0 = value head solo; blocks 1.. = all-pairs MFMA ----
  if (b == 0) {
    value_solo(h3, v1W, v1b, v2W, v2b, out + P, N, SMEM);
  } else {
    for (int wid = b - 1; wid < 1056; wid += GRID - 1)
      pair_work(wid, Abh, Bbh, W2h, p2b, p3W, p3b, out, N);
  }
}

// ---------------- host orchestration ----------------
extern "C" void kernel_launch(void* const* d_in, const int* in_sizes, int n_in,
                              void* d_out, int out_size, void* d_ws, size_t ws_size,
                              hipStream_t stream) {
  const float* x    = (const float*)d_in[0];
  const int*   ei   = (const int*)  d_in[1];
  const float* ea   = (const float*)d_in[2];
  const float* embW = (const float*)d_in[3];
  const float* embb = (const float*)d_in[4];
  const float* Wl   = (const float*)d_in[5];
  const float* bl   = (const float*)d_in[6];
  const float* Wr   = (const float*)d_in[7];
  const float* br   = (const float*)d_in[8];
  const float* We   = (const float*)d_in[9];
  const float* att  = (const float*)d_in[10];
  const float* gb   = (const float*)d_in[11];
  const float* lng  = (const float*)d_in[12];
  const float* lnb  = (const float*)d_in[13];
  const float* p1W  = (const float*)d_in[14];
  const float* p1b  = (const float*)d_in[15];
  const float* p2W  = (const float*)d_in[16];
  const float* p2b  = (const float*)d_in[17];
  const float* p3W  = (const float*)d_in[18];
  const float* p3b  = (const float*)d_in[19];
  const float* v1W  = (const float*)d_in[20];
  const float* v1b  = (const float*)d_in[21];
  const float* v2W  = (const float*)d_in[22];
  const float* v2b  = (const float*)d_in[23];
  const float* coup = (const float*)d_in[24];

  int N = in_sizes[0];         // 512
  int E = in_sizes[2] / 3;     // 260000
  float* out = (float*)d_out;

  // ---- workspace carve ----
  char* w = (char*)d_ws;
  int*    goA  = (int*)   (w + 0);         // 32x256B = 8192 (zeroed)
  int*    gcnt = (int*)   (w + 8192);      // 8192 -> 16384 (zeroed)
  int*    rcnt = (int*)   (w + 16384);     // 2048 -> 18432 (zeroed)
  float*  asum = (float*) (w + 18432);     // 6144 -> 24576 (zeroed)
  int*    dcol = (int*)   (w + 24576);     // 4096 -> 28672 (zeroed)
  float*  epart= (float*) (w + 28672);     // 8
  float*  ul   = (float*) (w + 28928);     // 1024
  float*  vl   = (float*) (w + 29952);     // 1024
  float*  ur   = (float*) (w + 30976);     // 1024
  float*  vr   = (float*) (w + 32000);     // 1024 -> 33024
  float4* csr  = (float4*)(w + 33024);     // 512*768*16 = 6291456 -> 6324480
  unsigned short* xlh = (unsigned short*)(w + 6324480); // 3x262144 -> 7110912
  unsigned short* Abh = (unsigned short*)(w + 7110912); // 262144 -> 7373056
  unsigned short* Bbh = (unsigned short*)(w + 7373056); // 262144 -> 7635200
  float* h3 = (float*)(w + 7635200);       // 524288 -> 8159488
  unsigned short* W2h = (unsigned short*)(w + 8159488); // 65536 -> 8225024
  unsigned short* Whall = (unsigned short*)(w + 8225024); // 1310720 -> 9535744

  zero_k<<<28, 256, 0, stream>>>((int*)w);   // goA+gcnt+rcnt+asum+dcol
  mega<<<GRID, 256, 0, stream>>>(
      x, ei, ea, embW, embb, Wl, bl, Wr, br, We, att, gb, lng, lnb,
      p1W, p1b, p2W, p2b, p3W, p3b, v1W, v1b, v2W, v2b, coup,
      rcnt, asum, dcol, epart, ul, vl, ur, vr, csr, xlh, Abh, Bbh, h3,
      W2h, Whall, goA, gcnt, out, N, E);
}

// Round 7
// 536.536 us; speedup vs baseline: 1.0001x; 1.0001x over previous
//
#include <hip/hip_runtime.h>
#include <math.h>

#define HDIM 256
#define NHEADS 8
#define NEG 0.2f
#define STRIDE 768   // padded CSR row stride (max degree ~590)
#define GRID 512     // persistent blocks, 1 node/block; __launch_bounds__(256,2)
#define NGRP 32      // barrier groups (16 blocks/group)

typedef float f32x4 __attribute__((ext_vector_type(4)));
typedef _Float16 f16x8 __attribute__((ext_vector_type(8)));
typedef __fp16 fp16v2 __attribute__((ext_vector_type(2)));

union H8 { f16x8 v8; fp16v2 v2[4]; _Float16 h[8]; };

#if __has_builtin(__builtin_amdgcn_fdot2)
#define FDOT2(a, b, c) __builtin_amdgcn_fdot2((a), (b), (c), false)
#else
__device__ __forceinline__ float FDOT2(fp16v2 a, fp16v2 b, float c) {
  return fmaf((float)a[1], (float)b[1], fmaf((float)a[0], (float)b[0], c));
}
#endif

// ---- write-through stores (relaxed agent atomics; cross-phase data) --------
__device__ __forceinline__ void st_u64(void* p, unsigned long long v) {
  __hip_atomic_store((unsigned long long*)p, v, __ATOMIC_RELAXED,
                     __HIP_MEMORY_SCOPE_AGENT);
}
__device__ __forceinline__ void st_f32(float* p, float v) {
  __hip_atomic_store(p, v, __ATOMIC_RELAXED, __HIP_MEMORY_SCOPE_AGENT);
}

// ---------------- zero scratch (goA + gcnt + rcnt + asum + dcol) -------------
__global__ __launch_bounds__(256) void zero_k(int* __restrict__ p) {
  p[blockIdx.x * 256 + threadIdx.x] = 0;
}

// ---------------- relaxed-only grid barrier with graduated poll backoff ------
// Agent-scope loads bypass L2 and round-trip the EA; dense polling congests
// the fabric that real work shares (R6 lesson: FETCH/WRITE ~ poll count).
// Backoff: 16 fast polls (s_sleep(2) ~128cy) then sparse (s_sleep(64) ~4096cy).
__device__ __forceinline__ void gbar(int* goA, int* gcnt, int ep) {
  __syncthreads();                       // drains vmcnt for every thread
  int t = threadIdx.x, b = blockIdx.x;
  int g = b >> 4;
  if (t == 0)
    __hip_atomic_fetch_add(&gcnt[g << 6], 1, __ATOMIC_RELAXED,
                           __HIP_MEMORY_SCOPE_AGENT);
  if (b == 0) {
    if (t < NGRP) {
      int it = 0;
      while (__hip_atomic_load(&gcnt[t << 6], __ATOMIC_RELAXED,
                               __HIP_MEMORY_SCOPE_AGENT) < ep * 16) {
        if (++it < 16) __builtin_amdgcn_s_sleep(2);
        else           __builtin_amdgcn_s_sleep(64);
      }
    }
    __syncthreads();
    if (t < NGRP)
      __hip_atomic_store(&goA[t << 6], ep, __ATOMIC_RELAXED,
                         __HIP_MEMORY_SCOPE_AGENT);
  } else if (t == 0) {
    int it = 0;
    while (__hip_atomic_load(&goA[g << 6], __ATOMIC_RELAXED,
                             __HIP_MEMORY_SCOPE_AGENT) < ep) {
      if (++it < 16) __builtin_amdgcn_s_sleep(2);
      else           __builtin_amdgcn_s_sleep(64);
    }
  }
  __syncthreads();
}

// ---------------- work: single-pass padded-CSR build (no self-loop slot) -----
__device__ __forceinline__ void build_work(int b, const int* ei, const float* ea,
    int E, int* rcnt, float* asum, int* dcol, float4* csr, char* SMEM) {
  int*   lcnt = (int*)SMEM;                 // 512
  float* ls0  = (float*)(SMEM + 2048);
  float* ls1  = (float*)(SMEM + 4096);
  float* ls2  = (float*)(SMEM + 6144);
  int*   lcol = (int*)(SMEM + 8192);        // 1024
  int*   lbase= (int*)(SMEM + 12288);       // 512 -> 14336 total
  int t = threadIdx.x;
  for (int n = t; n < 512; n += 256) {
    lcnt[n] = 0; ls0[n] = 0.f; ls1[n] = 0.f; ls2[n] = 0.f;
    lcol[n] = 0; lcol[512 + n] = 0;
  }
  __syncthreads();
  int e0 = b << 10, e1 = min(E, e0 + 1024);

  int nd[4], ns[4], slot[4];
  float va0[4], va1[4], va2[4];
#pragma unroll
  for (int k = 0; k < 4; ++k) {
    int e = e0 + t + (k << 8);
    if (e < e1) {
      int src = ei[e], dst = ei[E + e];
      float a0 = ea[3*e], a1 = ea[3*e+1], a2 = ea[3*e+2];
      nd[k] = dst; ns[k] = src; va0[k] = a0; va1[k] = a1; va2[k] = a2;
      slot[k] = atomicAdd(&lcnt[dst], 1);
      atomicAdd(&ls0[dst], a0);
      atomicAdd(&ls1[dst], a1);
      atomicAdd(&ls2[dst], a2);
      int idx = 0; float best = a0;
      if (a1 > best) { best = a1; idx = 1; }
      if (a2 > best) { idx = 2; }
      if (idx) {
        int o = (idx - 1) << 9;
        atomicAdd(&lcol[o + src], 1);
        atomicAdd(&lcol[o + dst], 1);
      }
    } else {
      nd[k] = -1;
    }
  }
  __syncthreads();
  for (int n = t; n < 512; n += 256) {
    int c = lcnt[n];
    if (c) {
      lbase[n] = atomicAdd(&rcnt[n], c);
      atomicAdd(&asum[n],        ls0[n]);
      atomicAdd(&asum[512 + n],  ls1[n]);
      atomicAdd(&asum[1024 + n], ls2[n]);
    }
    int c0 = lcol[n], c1 = lcol[512 + n];
    if (c0) atomicAdd(&dcol[n], c0);
    if (c1) atomicAdd(&dcol[512 + n], c1);
  }
  __syncthreads();
#pragma unroll
  for (int k = 0; k < 4; ++k) {
    if (nd[k] >= 0) {
      int pos = nd[k]*STRIDE + lbase[nd[k]] + slot[k];
      unsigned long long* p = (unsigned long long*)&csr[pos];
      union { float f[2]; unsigned long long u; } h0, h1;
      h0.f[0] = va0[k]; h0.f[1] = va1[k];
      h1.f[0] = va2[k]; h1.f[1] = __int_as_float(ns[k]);
      st_u64(p, h0.u);
      st_u64(p + 1, h1.u);
    }
  }
}

// ---------------- work: weight prep (dst-linear; Whall frag layout + W2h) ----
__device__ __forceinline__ void wprep_work(int wid, const float* Wl,
    const float* Wr, const float* p1W, const float* W2,
    unsigned short* dst, unsigned short* W2h) {
  int q = wid * 256 + (int)threadIdx.x;
  int base = q << 2;                        // 4 elements per thread
  const float* src; unsigned short* d; int k, n, stride;
  if (base < 10*65536) {
    int s = base >> 16, r = base & 65535;
    int kj = r & 7, lane = (r >> 3) & 63, c = (r >> 9) & 7, nt = r >> 12;
    src = (s < 4) ? (Wl + (size_t)s*65536)
        : (s < 8) ? (Wr + (size_t)(s-4)*65536)
                  : (p1W + (size_t)(s-8)*65536);
    k = c*32 + (lane >> 4)*8 + kj;
    n = nt*16 + (lane & 15);
    d = dst + base; stride = 256;
  } else {
    int off = base - 10*65536;
    int kj = off & 7, lane = (off >> 3) & 63, nt = (off >> 9) & 7, c = off >> 12;
    k = c*32 + (lane >> 4)*8 + kj;
    n = nt*16 + (lane & 15);
    src = W2; d = W2h + off; stride = 128;
  }
  union { fp16v2 v[2]; unsigned long long u; } uu;
  uu.v[0] = __builtin_amdgcn_cvt_pkrtz(src[(size_t)k*stride + n],
                                       src[(size_t)(k+1)*stride + n]);
  uu.v[1] = __builtin_amdgcn_cvt_pkrtz(src[(size_t)(k+2)*stride + n],
                                       src[(size_t)(k+3)*stride + n]);
  st_u64(d, uu.u);
}

// ---------------- work: rank-1 layer-0 maps  u=embW@W, v=embb@W+b ------------
__device__ __forceinline__ void embmap_work(int q, const float* Wl0,
    const float* Wr0, const float* embW, const float* embb,
    const float* bl0, const float* br0,
    float* ul, float* vl, float* ur, float* vr) {
  const float* W  = q ? Wr0 : Wl0;
  const float* bb = q ? br0 : bl0;
  float* u = q ? ur : ul;
  float* v = q ? vr : vl;
  int c = threadIdx.x;
  float su = 0.f, sv = 0.f;
  for (int k = 0; k < 256; ++k) {
    float wv = W[(size_t)k*256 + c];
    su = fmaf(embW[k], wv, su);
    sv = fmaf(embb[k], wv, sv);
  }
  st_f32(&u[c], su);
  st_f32(&v[c], sv + bb[c]);
}

// ---------------- online-softmax edge step (packed f16 scoring) --------------
__device__ __forceinline__ void edge_step(float rx, float ry, float rz,
    f16x8 cur, f16x8 xr8, const union H8& w0u, const union H8& w1u,
    const union H8& w2u, const union H8& avu,
    float& mh, float& lh, float* acc) {
  _Float16 hx = (_Float16)rx, hy = (_Float16)ry, hz = (_Float16)rz;
  f16x8 s = cur + xr8;
  s = s + w0u.v8 * hx;
  s = s + w1u.v8 * hy;
  s = s + w2u.v8 * hz;
  union H8 m;
  m.v8 = __builtin_elementwise_max(s, s * (_Float16)NEG);
  float partial = FDOT2(m.v2[3], avu.v2[3],
                  FDOT2(m.v2[2], avu.v2[2],
                  FDOT2(m.v2[1], avu.v2[1],
                  FDOT2(m.v2[0], avu.v2[0], 0.f))));
  partial += __shfl_xor(partial, 1);
  partial += __shfl_xor(partial, 2);
  if (partial - mh > 8.f) {
    float sc = __expf(mh - partial);
    lh *= sc;
#pragma unroll
    for (int j = 0; j < 8; ++j) acc[j] *= sc;
    mh = partial;
  }
  float pw = __expf(partial - mh);
  lh += pw;
  union H8 cu; cu.v8 = cur;
#pragma unroll
  for (int j = 0; j < 8; ++j) acc[j] = fmaf(pw, (float)cu.h[j], acc[j]);
}

// ---------------- work: all-pairs policy MLP via MFMA ------------------------
__device__ __forceinline__ void pair_work(int bb,
    const unsigned short* Ah, const unsigned short* Bh,
    const unsigned short* W2h, const float* b2, const float* W3,
    const float* b3, float* out, int N) {
  int half = bb & 1;
  int b = bb >> 1, ti = 0, rem = 32;
  while (b >= rem) { b -= rem; ti++; rem--; }
  int tj = ti + b;
  int i0 = ti * 16 + half * 8;
  int j0 = tj * 16;

  int t = threadIdx.x;
  int w = t >> 6, l = t & 63;
  int quad = l >> 4, nl = l & 15;

  float b2v[8], w3v[8];
#pragma unroll
  for (int nt = 0; nt < 8; ++nt) {
    b2v[nt] = b2[nt*16 + nl];
    w3v[nt] = W3[nt*16 + nl];
  }

  const unsigned short* Brow = Bh + (size_t)(j0 + nl) * HDIM;
  const unsigned short* Arow0 = Ah + (size_t)(i0 + w*2) * HDIM;
  const f16x8 zv = {};

  f32x4 acc[2][8];
#pragma unroll
  for (int a2 = 0; a2 < 2; ++a2)
#pragma unroll
    for (int nt = 0; nt < 8; ++nt) acc[a2][nt] = (f32x4){0.f,0.f,0.f,0.f};

  for (int c = 0; c < 8; ++c) {
    int kb = c*32 + quad*8;
    f16x8 bv = *(const f16x8*)(Brow + kb);

    f16x8 afrag[2];
#pragma unroll
    for (int a2 = 0; a2 < 2; ++a2) {
      f16x8 av = *(const f16x8*)(Arow0 + (size_t)a2*HDIM + kb);
      afrag[a2] = __builtin_elementwise_max(av + bv, zv);
    }

#pragma unroll
    for (int nt = 0; nt < 8; ++nt) {
      f16x8 bfrag = *(const f16x8*)(W2h + (size_t)(((c*8 + nt)*64 + l) * 8));
#pragma unroll
      for (int a2 = 0; a2 < 2; ++a2)
        acc[a2][nt] = __builtin_amdgcn_mfma_f32_16x16x32_f16(
            afrag[a2], bfrag, acc[a2][nt], 0, 0, 0);
    }
  }

  float b3v = b3[0];
#pragma unroll
  for (int a2 = 0; a2 < 2; ++a2) {
    int i = i0 + w*2 + a2;
#pragma unroll
    for (int r = 0; r < 4; ++r) {
      float s = 0.f;
#pragma unroll
      for (int nt = 0; nt < 8; ++nt)
        s = fmaf(fmaxf(acc[a2][nt][r] + b2v[nt], 0.f), w3v[nt], s);
      s += __shfl_xor(s, 1);
      s += __shfl_xor(s, 2);
      s += __shfl_xor(s, 4);
      s += __shfl_xor(s, 8);
      if (nl == 0) {
        int j = j0 + quad*4 + r;
        if (i < j)
          out[(size_t)i*(2*N - i - 1)/2 + (j - i - 1)] = s + b3v;
      }
    }
  }
}

// ---------------- work: value head solo (pool + MLP, one block) --------------
__device__ __forceinline__ void value_solo(const float* h3, const float* v1W,
    const float* v1b, const float* v2W, const float* v2b,
    float* out_val, int N, char* SMEM) {
  float* repr = (float*)SMEM;           // 512 f32
  float* wsum = (float*)(SMEM + 2048);  // 4 f32
  int t = threadIdx.x;
  float s = 0.f, m = -INFINITY;
  for (int nn = 0; nn < N; ++nn) {
    float v = h3[(size_t)nn*HDIM + t];
    s += v; m = fmaxf(m, v);
  }
  repr[t] = s / (float)N;
  repr[256 + t] = m;
  __syncthreads();
  float p = 0.f;
#pragma unroll 8
  for (int k = 0; k < 512; ++k)
    p = fmaf(repr[k], v1W[(size_t)k*HDIM + t], p);
  float a = fmaxf(p + v1b[t], 0.f);
  float pd = a * v2W[t];
#pragma unroll
  for (int off = 1; off < 64; off <<= 1) pd += __shfl_xor(pd, off);
  if ((t & 63) == 0) wsum[t >> 6] = pd;
  __syncthreads();
  if (t == 0) out_val[0] = wsum[0] + wsum[1] + wsum[2] + wsum[3] + v2b[0];
}

// ---------------- the persistent mega-kernel ---------------------------------
__global__ __launch_bounds__(256, 2) void mega(
    const float* __restrict__ x, const int* __restrict__ ei,
    const float* __restrict__ ea,
    const float* __restrict__ embW, const float* __restrict__ embb,
    const float* __restrict__ Wl, const float* __restrict__ bl,
    const float* __restrict__ Wr, const float* __restrict__ br,
    const float* __restrict__ We, const float* __restrict__ att,
    const float* __restrict__ gb, const float* __restrict__ lng,
    const float* __restrict__ lnb,
    const float* __restrict__ p1W, const float* __restrict__ p1b,
    const float* __restrict__ p2W, const float* __restrict__ p2b,
    const float* __restrict__ p3W, const float* __restrict__ p3b,
    const float* __restrict__ v1W, const float* __restrict__ v1b,
    const float* __restrict__ v2W, const float* __restrict__ v2b,
    const float* __restrict__ coup,
    int* rcnt, float* asum, int* dcol, float* epart,
    float* ul, float* vl, float* ur, float* vr,
    float4* csr, unsigned short* xlh,
    unsigned short* Abh, unsigned short* Bbh, float* h3,
    unsigned short* W2h, unsigned short* Whall,
    int* goA, int* gcnt,
    float* out, int N, int E) {
  __shared__ __align__(16) char SMEM[14336];
  float* lacc = (float*)SMEM;                       // 8192
  float* lm   = (float*)(SMEM + 8192);              // 256
  float* llv  = (float*)(SMEM + 8448);              // 256
  float* rs1  = (float*)(SMEM + 8704);              // 16
  float* rs2  = (float*)(SMEM + 8720);              // 16
  unsigned short* xl16 = (unsigned short*)(SMEM + 8736);  // 512
  unsigned short* xr16 = (unsigned short*)(SMEM + 9248);  // 512
  unsigned short* h16  = (unsigned short*)(SMEM + 9760);  // 512
  float* h32 = (float*)(SMEM + 10272);              // 1024

  size_t P = (size_t)N*(N-1)/2;
  int b = blockIdx.x, t = threadIdx.x;
  int ph = 0;

  // ---- P0: build CSR (254) + weight prep (672) + embmap (2) ----
  {
    int WB = (E + 1023) >> 10;
    int tot = WB + 672 + 2;
    for (int wid = b; wid < tot; wid += GRID) {
      if (wid < WB)            build_work(wid, ei, ea, E, rcnt, asum, dcol, csr, SMEM);
      else if (wid < WB + 672) wprep_work(wid - WB, Wl, Wr, p1W, p2W, Whall, W2h);
      else                     embmap_work(wid - WB - 672, Wl, Wr, embW, embb,
                                           bl, br, ul, vl, ur, vr);
    }
  }
  ++ph; gbar(goA, gcnt, ph);

  // ---- persistent per-thread state for node n = b ----
  int n = b;
  float h_prev = 0.f;
  int g = t >> 5, lane = t & 31, hd = lane >> 2, qd = lane & 3;
  int cb = hd*32 + qd*8;

  for (int l = 0; l < 4; ++l) {
    if (n < N) {
      // energy partials by blocks 0,1 at L0; energy final by block 0 at L1
      if (l == 0 && n < 2) {
        int id = n*256 + t;
        float e = 0.f;
        if (id < N) {
          float d1 = (float)dcol[id], d2 = (float)dcol[512 + id];
          e = d1*d1 + d2*d2;
        }
#pragma unroll
        for (int off = 1; off < 64; off <<= 1) e += __shfl_xor(e, off);
        if ((t & 63) == 0) rs1[t >> 6] = e;
        __syncthreads();
        if (t == 0) st_f32(&epart[n], rs1[0] + rs1[1] + rs1[2] + rs1[3]);
        __syncthreads();
      }
      if (l == 1 && n == 0 && t == 0) {
        float e0 = epart[0], e1 = epart[1];
        out[P + 1] = coup[0] * (e0 + e1) / (2.f * (float)N);
      }

      // -- entry: xl16/xr16 for this layer --
      if (l == 0) {
        float xv = x[n];
        float xl0 = fmaf(xv, ul[t], vl[t]);
        float xr0 = fmaf(xv, ur[t], vr[t]);
        _Float16 ha = (_Float16)xl0, hb = (_Float16)xr0;
        xl16[t] = *(unsigned short*)&ha;
        xr16[t] = *(unsigned short*)&hb;
        h_prev = fmaf(xv, embW[t], embb[t]);
      }
      __syncthreads();

      // -- gather setup --
      const float* Wel = We + (size_t)l*3*HDIM;
      const float* atl = att + (size_t)l*HDIM;
      union H8 w0u, w1u, w2u, avu;
#pragma unroll
      for (int p = 0; p < 4; ++p) {
        w0u.v2[p] = __builtin_amdgcn_cvt_pkrtz(Wel[cb+2*p],          Wel[cb+2*p+1]);
        w1u.v2[p] = __builtin_amdgcn_cvt_pkrtz(Wel[HDIM+cb+2*p],     Wel[HDIM+cb+2*p+1]);
        w2u.v2[p] = __builtin_amdgcn_cvt_pkrtz(Wel[2*HDIM+cb+2*p],   Wel[2*HDIM+cb+2*p+1]);
        avu.v2[p] = __builtin_amdgcn_cvt_pkrtz(atl[cb+2*p],          atl[cb+2*p+1]);
      }
      f16x8 xr8 = *(const f16x8*)(xr16 + cb);
      f16x8 xl8self = *(const f16x8*)(xl16 + cb);

      int cnt = rcnt[n];
      int base = n * STRIDE;
      int send = base + cnt;
      float mh = -INFINITY, lh = 0.f;
      float acc[8] = {0.f,0.f,0.f,0.f,0.f,0.f,0.f,0.f};

      if (g == 0) {                       // self-loop seed (mean edge_attr)
        float inv = 1.f / fmaxf((float)cnt, 1.f);
        edge_step(asum[n]*inv, asum[512+n]*inv, asum[1024+n]*inv,
                  xl8self, xr8, w0u, w1u, w2u, avu, mh, lh, acc);
      }

      if (l == 0) {
        // neighbor xl computed on the fly: xl0[src] = x[src]*ul + vl
        float ul8[8], vl8[8];
#pragma unroll
        for (int j = 0; j < 8; ++j) { ul8[j] = ul[cb+j]; vl8[j] = vl[cb+j]; }
        int idx = base + g;
        if (idx < send) {
          int i1 = idx + 8, i2 = idx + 16;
          float4 rec  = csr[idx];
          float4 rec1 = csr[i1 < send ? i1 : base];
          float4 rec2 = csr[i2 < send ? i2 : base];
          float xs  = x[__float_as_int(rec.w)];
          float xs1 = x[__float_as_int(rec1.w)];
          while (idx < send) {
            int i3 = i2 + 8;
            float4 rec3 = csr[i3 < send ? i3 : base];
            float xs2 = x[__float_as_int(rec2.w)];
            union H8 cur;
#pragma unroll
            for (int p = 0; p < 4; ++p)
              cur.v2[p] = __builtin_amdgcn_cvt_pkrtz(
                  fmaf(xs, ul8[2*p], vl8[2*p]),
                  fmaf(xs, ul8[2*p+1], vl8[2*p+1]));
            edge_step(rec.x, rec.y, rec.z, cur.v8, xr8, w0u, w1u, w2u, avu,
                      mh, lh, acc);
            rec = rec1; rec1 = rec2; rec2 = rec3;
            xs = xs1; xs1 = xs2;
            idx = i1; i1 = i2; i2 = i3;
          }
        }
      } else {
        const unsigned short* xg = xlh + (size_t)(l-1)*N*HDIM;
        int idx = base + g;
        if (idx < send) {
          int i1 = idx + 8, i2 = idx + 16;
          float4 rec  = csr[idx];
          float4 rec1 = csr[i1 < send ? i1 : base];
          float4 rec2 = csr[i2 < send ? i2 : base];
          union H8 cur, nxt, nx2;
          cur.v8 = *(const f16x8*)(xg + (size_t)__float_as_int(rec.w)*HDIM + cb);
          nxt.v8 = *(const f16x8*)(xg + (size_t)__float_as_int(rec1.w)*HDIM + cb);
          while (idx < send) {
            int i3 = i2 + 8;
            float4 rec3 = csr[i3 < send ? i3 : base];
            nx2.v8 = *(const f16x8*)(xg +
                      (size_t)__float_as_int(rec2.w)*HDIM + cb);
            edge_step(rec.x, rec.y, rec.z, cur.v8, xr8, w0u, w1u, w2u, avu,
                      mh, lh, acc);
            rec = rec1; rec1 = rec2; rec2 = rec3;
            cur.v8 = nxt.v8; nxt.v8 = nx2.v8;
            idx = i1; i1 = i2; i2 = i3;
          }
        }
      }

      // -- merge 8 group-partials --
#pragma unroll
      for (int j = 0; j < 8; ++j) lacc[g*HDIM + cb + j] = acc[j];
      if (qd == 0) { lm[g*NHEADS + hd] = mh; llv[g*NHEADS + hd] = lh; }
      __syncthreads();

      int c = t, hh = c >> 5;
      float M = -INFINITY;
#pragma unroll
      for (int g2 = 0; g2 < 8; ++g2) M = fmaxf(M, lm[g2*NHEADS + hh]);
      float L = 0.f, o = 0.f;
#pragma unroll
      for (int g2 = 0; g2 < 8; ++g2) {
        float e2 = __expf(lm[g2*NHEADS + hh] - M);
        L = fmaf(llv[g2*NHEADS + hh], e2, L);
        o = fmaf(lacc[g2*HDIM + c], e2, o);
      }
      float val = o / L + gb[l*HDIM + c] + h_prev;

      // -- LayerNorm + relu --
      float vs = val, vq = val * val;
#pragma unroll
      for (int off = 1; off < 64; off <<= 1) {
        vs += __shfl_xor(vs, off);
        vq += __shfl_xor(vq, off);
      }
      if ((t & 63) == 0) { rs1[t >> 6] = vs; rs2[t >> 6] = vq; }
      __syncthreads();
      float S1 = rs1[0] + rs1[1] + rs1[2] + rs1[3];
      float S2 = rs2[0] + rs2[1] + rs2[2] + rs2[3];
      float mu = S1 * (1.f/HDIM);
      float var = S2 * (1.f/HDIM) - mu * mu;
      float y = (val - mu) * rsqrtf(var + 1e-5f);
      y = fmaf(y, lng[l*HDIM + c], lnb[l*HDIM + c]);
      float h_new = fmaxf(y, 0.f);
      h_prev = h_new;
      h32[t] = h_new;
      _Float16 hh16 = (_Float16)h_new;
      h16[t] = *(unsigned short*)&hh16;
      __syncthreads();                    // h16 ready; xl16/xr16 reads done

      // -- fused next-op GEMM (FDOT2 vs Whall fragment layout) --
      const unsigned short* WhA;
      const unsigned short* WhB;
      const float* bA;
      const float* bB;
      if (l < 3) {
        WhA = Whall + (size_t)(l+1)*65536;
        WhB = Whall + (size_t)(4+l+1)*65536;
        bA = bl + (l+1)*HDIM; bB = br + (l+1)*HDIM;
      } else {
        WhA = Whall + (size_t)8*65536;
        WhB = Whall + (size_t)9*65536;
        bA = p1b; bB = nullptr;
      }
      int nt = t >> 4, nl = t & 15;
      const fp16v2* h2 = (const fp16v2*)h16;
      float accA = 0.f, accB = 0.f;
#pragma unroll
      for (int ccc = 0; ccc < 8; ++ccc) {
#pragma unroll
        for (int q = 0; q < 4; ++q) {
          size_t fo = (size_t)(nt*8 + ccc)*512 + (q*16 + nl)*8;
          union H8 wa, wb;
          wa.v8 = *(const f16x8*)(WhA + fo);
          wb.v8 = *(const f16x8*)(WhB + fo);
          int hb2 = ccc*16 + q*4;
#pragma unroll
          for (int p = 0; p < 4; ++p) {
            accA = FDOT2(wa.v2[p], h2[hb2 + p], accA);
            accB = FDOT2(wb.v2[p], h2[hb2 + p], accB);
          }
        }
      }
      float xlv = accA + bA[t];
      float xrv = accB + (bB ? bB[t] : 0.f);
      _Float16 ga16 = (_Float16)xlv, gb16 = (_Float16)xrv;
      xl16[t] = *(unsigned short*)&ga16;
      xr16[t] = *(unsigned short*)&gb16;
      __syncthreads();

      // -- write-through outputs --
      if (l < 3) {
        if (t < 64) {
          unsigned long long* dst =
              (unsigned long long*)(xlh + (size_t)l*N*HDIM + (size_t)n*HDIM);
          st_u64(&dst[t], ((const unsigned long long*)xl16)[t]);
        }
      } else {
        if (t < 64) {
          unsigned long long* dst =
              (unsigned long long*)(Abh + (size_t)n*HDIM);
          st_u64(&dst[t], ((const unsigned long long*)xl16)[t]);
        } else if (t < 128) {
          unsigned long long* dst =
              (unsigned long long*)(Bbh + (size_t)n*HDIM);
          st_u64(&dst[t-64], ((const unsigned long long*)xr16)[t-64]);
        } else {
          unsigned long long* dst =
              (unsigned long long*)(h3 + (size_t)n*HDIM);
          st_u64(&dst[t-128], ((const unsigned long long*)h32)[t-128]);
        }
      }
    }
    ++ph; gbar(goA, gcnt, ph);
  }

  // ---- FINAL: block 0 = value head solo; blocks 1.. = all-pairs MFMA ----
  if (b == 0) {
    value_solo(h3, v1W, v1b, v2W, v2b, out + P, N, SMEM);
  } else {
    for (int wid = b - 1; wid < 1056; wid += GRID - 1)
      pair_work(wid, Abh, Bbh, W2h, p2b, p3W, p3b, out, N);
  }
}

// ---------------- host orchestration ----------------
extern "C" void kernel_launch(void* const* d_in, const int* in_sizes, int n_in,
                              void* d_out, int out_size, void* d_ws, size_t ws_size,
                              hipStream_t stream) {
  const float* x    = (const float*)d_in[0];
  const int*   ei   = (const int*)  d_in[1];
  const float* ea   = (const float*)d_in[2];
  const float* embW = (const float*)d_in[3];
  const float* embb = (const float*)d_in[4];
  const float* Wl   = (const float*)d_in[5];
  const float* bl   = (const float*)d_in[6];
  const float* Wr   = (const float*)d_in[7];
  const float* br   = (const float*)d_in[8];
  const float* We   = (const float*)d_in[9];
  const float* att  = (const float*)d_in[10];
  const float* gb   = (const float*)d_in[11];
  const float* lng  = (const float*)d_in[12];
  const float* lnb  = (const float*)d_in[13];
  const float* p1W  = (const float*)d_in[14];
  const float* p1b  = (const float*)d_in[15];
  const float* p2W  = (const float*)d_in[16];
  const float* p2b  = (const float*)d_in[17];
  const float* p3W  = (const float*)d_in[18];
  const float* p3b  = (const float*)d_in[19];
  const float* v1W  = (const float*)d_in[20];
  const float* v1b  = (const float*)d_in[21];
  const float* v2W  = (const float*)d_in[22];
  const float* v2b  = (const float*)d_in[23];
  const float* coup = (const float*)d_in[24];

  int N = in_sizes[0];         // 512
  int E = in_sizes[2] / 3;     // 260000
  float* out = (float*)d_out;

  // ---- workspace carve ----
  char* w = (char*)d_ws;
  int*    goA  = (int*)   (w + 0);         // 32x256B = 8192 (zeroed)
  int*    gcnt = (int*)   (w + 8192);      // 8192 -> 16384 (zeroed)
  int*    rcnt = (int*)   (w + 16384);     // 2048 -> 18432 (zeroed)
  float*  asum = (float*) (w + 18432);     // 6144 -> 24576 (zeroed)
  int*    dcol = (int*)   (w + 24576);     // 4096 -> 28672 (zeroed)
  float*  epart= (float*) (w + 28672);     // 8
  float*  ul   = (float*) (w + 28928);     // 1024
  float*  vl   = (float*) (w + 29952);     // 1024
  float*  ur   = (float*) (w + 30976);     // 1024
  float*  vr   = (float*) (w + 32000);     // 1024 -> 33024
  float4* csr  = (float4*)(w + 33024);     // 512*768*16 = 6291456 -> 6324480
  unsigned short* xlh = (unsigned short*)(w + 6324480); // 3x262144 -> 7110912
  unsigned short* Abh = (unsigned short*)(w + 7110912); // 262144 -> 7373056
  unsigned short* Bbh = (unsigned short*)(w + 7373056); // 262144 -> 7635200
  float* h3 = (float*)(w + 7635200);       // 524288 -> 8159488
  unsigned short* W2h = (unsigned short*)(w + 8159488); // 65536 -> 8225024
  unsigned short* Whall = (unsigned short*)(w + 8225024); // 1310720 -> 9535744

  zero_k<<<28, 256, 0, stream>>>((int*)w);   // goA+gcnt+rcnt+asum+dcol
  mega<<<GRID, 256, 0, stream>>>(
      x, ei, ea, embW, embb, Wl, bl, Wr, br, We, att, gb, lng, lnb,
      p1W, p1b, p2W, p2b, p3W, p3b, v1W, v1b, v2W, v2b, coup,
      rcnt, asum, dcol, epart, ul, vl, ur, vr, csr, xlh, Abh, Bbh, h3,
      W2h, Whall, goA, gcnt, out, N, E);
}

// Round 8
// 380.281 us; speedup vs baseline: 1.4111x; 1.4109x over previous
//
#include <hip/hip_runtime.h>
#include <math.h>

#define HDIM 256
#define NHEADS 8
#define NEG 0.2f
#define STRIDE 768   // padded CSR row stride (max degree ~590)

typedef float f32x4 __attribute__((ext_vector_type(4)));
typedef _Float16 f16x8 __attribute__((ext_vector_type(8)));
typedef __fp16 fp16v2 __attribute__((ext_vector_type(2)));

union H8 { f16x8 v8; fp16v2 v2[4]; _Float16 h[8]; };

#if __has_builtin(__builtin_amdgcn_fdot2)
#define FDOT2(a, b, c) __builtin_amdgcn_fdot2((a), (b), (c), false)
#else
__device__ __forceinline__ float FDOT2(fp16v2 a, fp16v2 b, float c) {
  return fmaf((float)a[1], (float)b[1], fmaf((float)a[0], (float)b[0], c));
}
#endif

// ---------------- zero scratch (rcnt + asum + dcol: 3072 ints) ---------------
__global__ __launch_bounds__(256) void zero_k(int* __restrict__ p) {
  p[blockIdx.x * 256 + threadIdx.x] = 0;
}

// ---------------- prep: CSR build (254) + weight prep (672) + embmap (2) -----
__global__ __launch_bounds__(256) void prep_k(
    const int* __restrict__ ei, const float* __restrict__ ea, int E,
    const float* __restrict__ Wl, const float* __restrict__ Wr,
    const float* __restrict__ p1W, const float* __restrict__ W2,
    const float* __restrict__ embW, const float* __restrict__ embb,
    const float* __restrict__ bl, const float* __restrict__ br,
    int* __restrict__ rcnt, float* __restrict__ asum, int* __restrict__ dcol,
    float4* __restrict__ csr,
    unsigned short* __restrict__ Whall, unsigned short* __restrict__ W2h,
    float* __restrict__ ul, float* __restrict__ vl,
    float* __restrict__ ur, float* __restrict__ vr) {
  __shared__ __align__(16) char SMEM[14336];
  int wid = blockIdx.x;
  int WB = (E + 1023) >> 10;
  int t = threadIdx.x;

  if (wid < WB) {
    // ---- single-pass padded-CSR build ----
    int*   lcnt = (int*)SMEM;
    float* ls0  = (float*)(SMEM + 2048);
    float* ls1  = (float*)(SMEM + 4096);
    float* ls2  = (float*)(SMEM + 6144);
    int*   lcol = (int*)(SMEM + 8192);
    int*   lbase= (int*)(SMEM + 12288);
    for (int n = t; n < 512; n += 256) {
      lcnt[n] = 0; ls0[n] = 0.f; ls1[n] = 0.f; ls2[n] = 0.f;
      lcol[n] = 0; lcol[512 + n] = 0;
    }
    __syncthreads();
    int e0 = wid << 10, e1 = min(E, e0 + 1024);
    int nd[4], ns[4], slot[4];
    float va0[4], va1[4], va2[4];
#pragma unroll
    for (int k = 0; k < 4; ++k) {
      int e = e0 + t + (k << 8);
      if (e < e1) {
        int src = ei[e], dst = ei[E + e];
        float a0 = ea[3*e], a1 = ea[3*e+1], a2 = ea[3*e+2];
        nd[k] = dst; ns[k] = src; va0[k] = a0; va1[k] = a1; va2[k] = a2;
        slot[k] = atomicAdd(&lcnt[dst], 1);
        atomicAdd(&ls0[dst], a0);
        atomicAdd(&ls1[dst], a1);
        atomicAdd(&ls2[dst], a2);
        int idx = 0; float best = a0;
        if (a1 > best) { best = a1; idx = 1; }
        if (a2 > best) { idx = 2; }
        if (idx) {
          int o = (idx - 1) << 9;
          atomicAdd(&lcol[o + src], 1);
          atomicAdd(&lcol[o + dst], 1);
        }
      } else {
        nd[k] = -1;
      }
    }
    __syncthreads();
    for (int n = t; n < 512; n += 256) {
      int c = lcnt[n];
      if (c) {
        lbase[n] = atomicAdd(&rcnt[n], c);
        atomicAdd(&asum[n],        ls0[n]);
        atomicAdd(&asum[512 + n],  ls1[n]);
        atomicAdd(&asum[1024 + n], ls2[n]);
      }
      int c0 = lcol[n], c1 = lcol[512 + n];
      if (c0) atomicAdd(&dcol[n], c0);
      if (c1) atomicAdd(&dcol[512 + n], c1);
    }
    __syncthreads();
#pragma unroll
    for (int k = 0; k < 4; ++k) {
      if (nd[k] >= 0) {
        int pos = nd[k]*STRIDE + lbase[nd[k]] + slot[k];
        csr[pos] = make_float4(va0[k], va1[k], va2[k], __int_as_float(ns[k]));
      }
    }
  } else if (wid < WB + 672) {
    // ---- weight prep (dst-linear, 4 elems/thread, coalesced u64 store) ----
    int q = (wid - WB) * 256 + t;
    int base = q << 2;
    const float* src; unsigned short* d; int k, n, stride;
    if (base < 10*65536) {
      int s = base >> 16, r = base & 65535;
      int kj = r & 7, lane = (r >> 3) & 63, c = (r >> 9) & 7, nt = r >> 12;
      src = (s < 4) ? (Wl + (size_t)s*65536)
          : (s < 8) ? (Wr + (size_t)(s-4)*65536)
                    : (p1W + (size_t)(s-8)*65536);
      k = c*32 + (lane >> 4)*8 + kj;
      n = nt*16 + (lane & 15);
      d = Whall + base; stride = 256;
    } else {
      int off = base - 10*65536;
      int kj = off & 7, lane = (off >> 3) & 63, nt = (off >> 9) & 7, c = off >> 12;
      k = c*32 + (lane >> 4)*8 + kj;
      n = nt*16 + (lane & 15);
      src = W2; d = W2h + off; stride = 128;
    }
    union { fp16v2 v[2]; unsigned long long u; } uu;
    uu.v[0] = __builtin_amdgcn_cvt_pkrtz(src[(size_t)k*stride + n],
                                         src[(size_t)(k+1)*stride + n]);
    uu.v[1] = __builtin_amdgcn_cvt_pkrtz(src[(size_t)(k+2)*stride + n],
                                         src[(size_t)(k+3)*stride + n]);
    *(unsigned long long*)d = uu.u;
  } else {
    // ---- rank-1 layer-0 maps: u = embW@W, v = embb@W + b ----
    int q = wid - WB - 672;
    const float* W  = q ? Wr : Wl;
    const float* bb = q ? br : bl;
    float* u = q ? ur : ul;
    float* v = q ? vr : vl;
    float su = 0.f, sv = 0.f;
    for (int k = 0; k < 256; ++k) {
      float wv = W[(size_t)k*256 + t];
      su = fmaf(embW[k], wv, su);
      sv = fmaf(embb[k], wv, sv);
    }
    u[t] = su;
    v[t] = sv + bb[t];
  }
}

// ---------------- online-softmax edge step (packed f16 scoring) --------------
__device__ __forceinline__ void edge_step(float rx, float ry, float rz,
    f16x8 cur, f16x8 xr8, const union H8& w0u, const union H8& w1u,
    const union H8& w2u, const union H8& avu,
    float& mh, float& lh, float* acc) {
  _Float16 hx = (_Float16)rx, hy = (_Float16)ry, hz = (_Float16)rz;
  f16x8 s = cur + xr8;
  s = s + w0u.v8 * hx;
  s = s + w1u.v8 * hy;
  s = s + w2u.v8 * hz;
  union H8 m;
  m.v8 = __builtin_elementwise_max(s, s * (_Float16)NEG);
  float partial = FDOT2(m.v2[3], avu.v2[3],
                  FDOT2(m.v2[2], avu.v2[2],
                  FDOT2(m.v2[1], avu.v2[1],
                  FDOT2(m.v2[0], avu.v2[0], 0.f))));
  partial += __shfl_xor(partial, 1);
  partial += __shfl_xor(partial, 2);
  if (partial - mh > 8.f) {
    float sc = __expf(mh - partial);
    lh *= sc;
#pragma unroll
    for (int j = 0; j < 8; ++j) acc[j] *= sc;
    mh = partial;
  }
  float pw = __expf(partial - mh);
  lh += pw;
  union H8 cu; cu.v8 = cur;
#pragma unroll
  for (int j = 0; j < 8; ++j) acc[j] = fmaf(pw, (float)cu.h[j], acc[j]);
}

// ---------------- shared tail: merge partials + LN + fused next-GEMM ---------
// Returns nothing; writes h_out row (f32) and xl_out/xr_out rows (f16 u16).
__device__ __forceinline__ void merge_ln_gemm(int n, int t, float mh, float lh,
    float* acc, float h_prev,
    const float* gbl, const float* lngl, const float* lnbl,
    const unsigned short* WhA, const unsigned short* WhB,
    const float* bA, const float* bB,
    float* h_out, unsigned short* xl_out, unsigned short* xr_out,
    float* lacc, float* lm, float* llv, float* rs1, float* rs2,
    unsigned short* h16) {
  int g = t >> 5, lane = t & 31, hd = lane >> 2, qd = lane & 3;
  int cb = hd*32 + qd*8;
#pragma unroll
  for (int j = 0; j < 8; ++j) lacc[g*HDIM + cb + j] = acc[j];
  if (qd == 0) { lm[g*NHEADS + hd] = mh; llv[g*NHEADS + hd] = lh; }
  __syncthreads();

  int c = t, hh = c >> 5;
  float M = -INFINITY;
#pragma unroll
  for (int g2 = 0; g2 < 8; ++g2) M = fmaxf(M, lm[g2*NHEADS + hh]);
  float L = 0.f, o = 0.f;
#pragma unroll
  for (int g2 = 0; g2 < 8; ++g2) {
    float e2 = __expf(lm[g2*NHEADS + hh] - M);
    L = fmaf(llv[g2*NHEADS + hh], e2, L);
    o = fmaf(lacc[g2*HDIM + c], e2, o);
  }
  float val = o / L + gbl[c] + h_prev;

  float vs = val, vq = val * val;
#pragma unroll
  for (int off = 1; off < 64; off <<= 1) {
    vs += __shfl_xor(vs, off);
    vq += __shfl_xor(vq, off);
  }
  if ((t & 63) == 0) { rs1[t >> 6] = vs; rs2[t >> 6] = vq; }
  __syncthreads();
  float S1 = rs1[0] + rs1[1] + rs1[2] + rs1[3];
  float S2 = rs2[0] + rs2[1] + rs2[2] + rs2[3];
  float mu = S1 * (1.f/HDIM);
  float var = S2 * (1.f/HDIM) - mu * mu;
  float y = (val - mu) * rsqrtf(var + 1e-5f);
  y = fmaf(y, lngl[c], lnbl[c]);
  float h_new = fmaxf(y, 0.f);
  h_out[(size_t)n*HDIM + c] = h_new;
  _Float16 hh16 = (_Float16)h_new;
  h16[t] = *(unsigned short*)&hh16;
  __syncthreads();

  // fused next-op GEMM: out_ch t of xl/xr for the NEXT layer (or pair head)
  int nt = t >> 4, nl = t & 15;
  const fp16v2* h2 = (const fp16v2*)h16;
  float accA = 0.f, accB = 0.f;
#pragma unroll
  for (int ccc = 0; ccc < 8; ++ccc) {
#pragma unroll
    for (int q = 0; q < 4; ++q) {
      size_t fo = (size_t)(nt*8 + ccc)*512 + (q*16 + nl)*8;
      union H8 wa, wb;
      wa.v8 = *(const f16x8*)(WhA + fo);
      wb.v8 = *(const f16x8*)(WhB + fo);
      int hb2 = ccc*16 + q*4;
#pragma unroll
      for (int p = 0; p < 4; ++p) {
        accA = FDOT2(wa.v2[p], h2[hb2 + p], accA);
        accB = FDOT2(wb.v2[p], h2[hb2 + p], accB);
      }
    }
  }
  float xlv = accA + bA[t];
  float xrv = accB + (bB ? bB[t] : 0.f);
  _Float16 ga16 = (_Float16)xlv, gb16 = (_Float16)xrv;
  xl_out[(size_t)n*HDIM + t] = *(unsigned short*)&ga16;
  xr_out[(size_t)n*HDIM + t] = *(unsigned short*)&gb16;
}

// ---------------- gm0: layer-0 gather (rank-1 on-the-fly) + LN + GEMM --------
__global__ __launch_bounds__(256, 2) void gm0_k(
    const float* __restrict__ x,
    const float* __restrict__ embW, const float* __restrict__ embb,
    const float* __restrict__ ul, const float* __restrict__ vl,
    const float* __restrict__ ur, const float* __restrict__ vr,
    const float4* __restrict__ csr, const int* __restrict__ rcnt,
    const float* __restrict__ asum, const int* __restrict__ dcol,
    const float* __restrict__ We, const float* __restrict__ att,
    const float* __restrict__ gbl, const float* __restrict__ lngl,
    const float* __restrict__ lnbl,
    const unsigned short* __restrict__ WhA, const unsigned short* __restrict__ WhB,
    const float* __restrict__ bA, const float* __restrict__ bB,
    float* __restrict__ h_out, unsigned short* __restrict__ xl_out,
    unsigned short* __restrict__ xr_out,
    float* __restrict__ epart, int N) {
  __shared__ float lacc[8*HDIM];
  __shared__ float lm[8*NHEADS], llv[8*NHEADS];
  __shared__ float rs1[4], rs2[4];
  __shared__ unsigned short xl16[HDIM], xr16[HDIM], h16[HDIM];

  int n = blockIdx.x, t = threadIdx.x;

  // energy partials (blocks 0,1) from dcol
  if (n < 2) {
    int id = n*256 + t;
    float e = 0.f;
    if (id < N) {
      float d1 = (float)dcol[id], d2 = (float)dcol[512 + id];
      e = d1*d1 + d2*d2;
    }
#pragma unroll
    for (int off = 1; off < 64; off <<= 1) e += __shfl_xor(e, off);
    if ((t & 63) == 0) rs1[t >> 6] = e;
    __syncthreads();
    if (t == 0) epart[n] = rs1[0] + rs1[1] + rs1[2] + rs1[3];
    __syncthreads();
  }

  float xv = x[n];
  float xl0 = fmaf(xv, ul[t], vl[t]);
  float xr0 = fmaf(xv, ur[t], vr[t]);
  _Float16 ha = (_Float16)xl0, hb = (_Float16)xr0;
  xl16[t] = *(unsigned short*)&ha;
  xr16[t] = *(unsigned short*)&hb;
  float h_prev = fmaf(xv, embW[t], embb[t]);
  __syncthreads();

  int g = t >> 5, lane = t & 31, hd = lane >> 2, qd = lane & 3;
  int cb = hd*32 + qd*8;

  union H8 w0u, w1u, w2u, avu;
#pragma unroll
  for (int p = 0; p < 4; ++p) {
    w0u.v2[p] = __builtin_amdgcn_cvt_pkrtz(We[cb+2*p],        We[cb+2*p+1]);
    w1u.v2[p] = __builtin_amdgcn_cvt_pkrtz(We[HDIM+cb+2*p],   We[HDIM+cb+2*p+1]);
    w2u.v2[p] = __builtin_amdgcn_cvt_pkrtz(We[2*HDIM+cb+2*p], We[2*HDIM+cb+2*p+1]);
    avu.v2[p] = __builtin_amdgcn_cvt_pkrtz(att[cb+2*p],       att[cb+2*p+1]);
  }
  f16x8 xr8 = *(const f16x8*)(xr16 + cb);
  f16x8 xl8self = *(const f16x8*)(xl16 + cb);

  int cnt = rcnt[n];
  int base = n * STRIDE;
  int send = base + cnt;
  float mh = -INFINITY, lh = 0.f;
  float acc[8] = {0.f,0.f,0.f,0.f,0.f,0.f,0.f,0.f};

  if (g == 0) {
    float inv = 1.f / fmaxf((float)cnt, 1.f);
    edge_step(asum[n]*inv, asum[512+n]*inv, asum[1024+n]*inv,
              xl8self, xr8, w0u, w1u, w2u, avu, mh, lh, acc);
  }

  float ul8[8], vl8[8];
#pragma unroll
  for (int j = 0; j < 8; ++j) { ul8[j] = ul[cb+j]; vl8[j] = vl[cb+j]; }
  int idx = base + g;
  if (idx < send) {
    int i1 = idx + 8, i2 = idx + 16;
    float4 rec  = csr[idx];
    float4 rec1 = csr[i1 < send ? i1 : base];
    float4 rec2 = csr[i2 < send ? i2 : base];
    float xs  = x[__float_as_int(rec.w)];
    float xs1 = x[__float_as_int(rec1.w)];
    while (idx < send) {
      int i3 = i2 + 8;
      float4 rec3 = csr[i3 < send ? i3 : base];
      float xs2 = x[__float_as_int(rec2.w)];
      union H8 cur;
#pragma unroll
      for (int p = 0; p < 4; ++p)
        cur.v2[p] = __builtin_amdgcn_cvt_pkrtz(
            fmaf(xs, ul8[2*p], vl8[2*p]),
            fmaf(xs, ul8[2*p+1], vl8[2*p+1]));
      edge_step(rec.x, rec.y, rec.z, cur.v8, xr8, w0u, w1u, w2u, avu,
                mh, lh, acc);
      rec = rec1; rec1 = rec2; rec2 = rec3;
      xs = xs1; xs1 = xs2;
      idx = i1; i1 = i2; i2 = i3;
    }
  }

  merge_ln_gemm(n, t, mh, lh, acc, h_prev, gbl, lngl, lnbl,
                WhA, WhB, bA, bB, h_out, xl_out, xr_out,
                lacc, lm, llv, rs1, rs2, h16);
}

// ---------------- gm: generic layer gather + LN + fused GEMM -----------------
__global__ __launch_bounds__(256, 2) void gm_k(
    const unsigned short* __restrict__ xl_in, const unsigned short* __restrict__ xr_in,
    const float* __restrict__ h_in,
    const float4* __restrict__ csr, const int* __restrict__ rcnt,
    const float* __restrict__ asum,
    const float* __restrict__ We, const float* __restrict__ att,
    const float* __restrict__ gbl, const float* __restrict__ lngl,
    const float* __restrict__ lnbl,
    const unsigned short* __restrict__ WhA, const unsigned short* __restrict__ WhB,
    const float* __restrict__ bA, const float* __restrict__ bB,
    float* __restrict__ h_out, unsigned short* __restrict__ xl_out,
    unsigned short* __restrict__ xr_out,
    const float* __restrict__ epart, const float* __restrict__ coup,
    float* __restrict__ eout, int N) {
  __shared__ float lacc[8*HDIM];
  __shared__ float lm[8*NHEADS], llv[8*NHEADS];
  __shared__ float rs1[4], rs2[4];
  __shared__ unsigned short h16[HDIM];

  int n = blockIdx.x, t = threadIdx.x;
  if (eout && n == 0 && t == 0)
    eout[0] = coup[0] * (epart[0] + epart[1]) / (2.f * (float)N);

  int g = t >> 5, lane = t & 31, hd = lane >> 2, qd = lane & 3;
  int cb = hd*32 + qd*8;

  union H8 w0u, w1u, w2u, avu;
#pragma unroll
  for (int p = 0; p < 4; ++p) {
    w0u.v2[p] = __builtin_amdgcn_cvt_pkrtz(We[cb+2*p],        We[cb+2*p+1]);
    w1u.v2[p] = __builtin_amdgcn_cvt_pkrtz(We[HDIM+cb+2*p],   We[HDIM+cb+2*p+1]);
    w2u.v2[p] = __builtin_amdgcn_cvt_pkrtz(We[2*HDIM+cb+2*p], We[2*HDIM+cb+2*p+1]);
    avu.v2[p] = __builtin_amdgcn_cvt_pkrtz(att[cb+2*p],       att[cb+2*p+1]);
  }
  f16x8 xr8 = *(const f16x8*)(xr_in + (size_t)n*HDIM + cb);
  f16x8 xl8self = *(const f16x8*)(xl_in + (size_t)n*HDIM + cb);
  float h_prev = h_in[(size_t)n*HDIM + t];

  int cnt = rcnt[n];
  int base = n * STRIDE;
  int send = base + cnt;
  float mh = -INFINITY, lh = 0.f;
  float acc[8] = {0.f,0.f,0.f,0.f,0.f,0.f,0.f,0.f};

  if (g == 0) {
    float inv = 1.f / fmaxf((float)cnt, 1.f);
    edge_step(asum[n]*inv, asum[512+n]*inv, asum[1024+n]*inv,
              xl8self, xr8, w0u, w1u, w2u, avu, mh, lh, acc);
  }

  int idx = base + g;
  if (idx < send) {
    int i1 = idx + 8, i2 = idx + 16;
    float4 rec  = csr[idx];
    float4 rec1 = csr[i1 < send ? i1 : base];
    float4 rec2 = csr[i2 < send ? i2 : base];
    union H8 cur, nxt, nx2;
    cur.v8 = *(const f16x8*)(xl_in + (size_t)__float_as_int(rec.w)*HDIM + cb);
    nxt.v8 = *(const f16x8*)(xl_in + (size_t)__float_as_int(rec1.w)*HDIM + cb);
    while (idx < send) {
      int i3 = i2 + 8;
      float4 rec3 = csr[i3 < send ? i3 : base];
      nx2.v8 = *(const f16x8*)(xl_in +
                (size_t)__float_as_int(rec2.w)*HDIM + cb);
      edge_step(rec.x, rec.y, rec.z, cur.v8, xr8, w0u, w1u, w2u, avu,
                mh, lh, acc);
      rec = rec1; rec1 = rec2; rec2 = rec3;
      cur.v8 = nxt.v8; nxt.v8 = nx2.v8;
      idx = i1; i1 = i2; i2 = i3;
    }
  }

  merge_ln_gemm(n, t, mh, lh, acc, h_prev, gbl, lngl, lnbl,
                WhA, WhB, bA, bB, h_out, xl_out, xr_out,
                lacc, lm, llv, rs1, rs2, h16);
}

// ---------------- all-pairs policy MLP via MFMA (f16 A/B, no LDS) ------------
__global__ __launch_bounds__(256, 4) void pair_mfma_kernel(
    const unsigned short* __restrict__ Ah, const unsigned short* __restrict__ Bh,
    const unsigned short* __restrict__ W2h,
    const float* __restrict__ b2, const float* __restrict__ W3,
    const float* __restrict__ b3, float* __restrict__ out, int N) {
  int bb = blockIdx.x;
  int half = bb & 1;
  int b = bb >> 1, ti = 0, rem = 32;
  while (b >= rem) { b -= rem; ti++; rem--; }
  int tj = ti + b;
  int i0 = ti * 16 + half * 8;
  int j0 = tj * 16;

  int t = threadIdx.x;
  int w = t >> 6, l = t & 63;
  int quad = l >> 4, nl = l & 15;

  float b2v[8], w3v[8];
#pragma unroll
  for (int nt = 0; nt < 8; ++nt) {
    b2v[nt] = b2[nt*16 + nl];
    w3v[nt] = W3[nt*16 + nl];
  }

  const unsigned short* Brow = Bh + (size_t)(j0 + nl) * HDIM;
  const unsigned short* Arow0 = Ah + (size_t)(i0 + w*2) * HDIM;
  const f16x8 zv = {};

  f32x4 acc[2][8];
#pragma unroll
  for (int a2 = 0; a2 < 2; ++a2)
#pragma unroll
    for (int nt = 0; nt < 8; ++nt) acc[a2][nt] = (f32x4){0.f,0.f,0.f,0.f};

  for (int c = 0; c < 8; ++c) {
    int kb = c*32 + quad*8;
    f16x8 bv = *(const f16x8*)(Brow + kb);

    f16x8 afrag[2];
#pragma unroll
    for (int a2 = 0; a2 < 2; ++a2) {
      f16x8 av = *(const f16x8*)(Arow0 + (size_t)a2*HDIM + kb);
      afrag[a2] = __builtin_elementwise_max(av + bv, zv);
    }

#pragma unroll
    for (int nt = 0; nt < 8; ++nt) {
      f16x8 bfrag = *(const f16x8*)(W2h + (size_t)(((c*8 + nt)*64 + l) * 8));
#pragma unroll
      for (int a2 = 0; a2 < 2; ++a2)
        acc[a2][nt] = __builtin_amdgcn_mfma_f32_16x16x32_f16(
            afrag[a2], bfrag, acc[a2][nt], 0, 0, 0);
    }
  }

  float b3v = b3[0];
#pragma unroll
  for (int a2 = 0; a2 < 2; ++a2) {
    int i = i0 + w*2 + a2;
#pragma unroll
    for (int r = 0; r < 4; ++r) {
      float s = 0.f;
#pragma unroll
      for (int nt = 0; nt < 8; ++nt)
        s = fmaf(fmaxf(acc[a2][nt][r] + b2v[nt], 0.f), w3v[nt], s);
      s += __shfl_xor(s, 1);
      s += __shfl_xor(s, 2);
      s += __shfl_xor(s, 4);
      s += __shfl_xor(s, 8);
      if (nl == 0) {
        int j = j0 + quad*4 + r;
        if (i < j)
          out[(size_t)i*(2*N - i - 1)/2 + (j - i - 1)] = s + b3v;
      }
    }
  }
}

// ---------------- value head, stage 1: pooling partials (32 blocks) ----------
__global__ __launch_bounds__(256) void pool_kernel(
    const float* __restrict__ h, float* __restrict__ psums,
    float* __restrict__ pmaxs) {
  int g = blockIdx.x, t = threadIdx.x;
  float s = 0.f, m = -INFINITY;
#pragma unroll
  for (int r = 0; r < 16; ++r) {
    float v = h[(size_t)(g*16 + r)*HDIM + t];
    s += v; m = fmaxf(m, v);
  }
  psums[g*HDIM + t] = s;
  pmaxs[g*HDIM + t] = m;
}

// ---------------- value head, stage 2: partial matvec (32 blocks) ------------
__global__ __launch_bounds__(256) void value1_kernel(
    const float* __restrict__ psums, const float* __restrict__ pmaxs,
    const float* __restrict__ v1W, float* __restrict__ vpart, int N) {
  int b = blockIdx.x, t = threadIdx.x;
  int k0 = b * 16;
  int kk = t >> 4, g = t & 15;
  __shared__ float repr16[16];
  int k = k0 + kk;
  float v;
  if (k < HDIM) {
    v = psums[g*HDIM + k] + psums[(g + 16)*HDIM + k];
    v += __shfl_xor(v, 1); v += __shfl_xor(v, 2);
    v += __shfl_xor(v, 4); v += __shfl_xor(v, 8);
    if (g == 0) repr16[kk] = v / (float)N;
  } else {
    int kc = k - HDIM;
    v = fmaxf(pmaxs[g*HDIM + kc], pmaxs[(g + 16)*HDIM + kc]);
    v = fmaxf(v, __shfl_xor(v, 1)); v = fmaxf(v, __shfl_xor(v, 2));
    v = fmaxf(v, __shfl_xor(v, 4)); v = fmaxf(v, __shfl_xor(v, 8));
    if (g == 0) repr16[kk] = v;
  }
  __syncthreads();
  float pv = 0.f;
#pragma unroll
  for (int q = 0; q < 16; ++q)
    pv = fmaf(repr16[q], v1W[(size_t)(k0 + q)*HDIM + t], pv);
  vpart[b*HDIM + t] = pv;
}

// ---------------- value head, stage 3: finish (1 block) ----------------------
__global__ __launch_bounds__(256) void value2_kernel(
    const float* __restrict__ vpart, const float* __restrict__ v1b,
    const float* __restrict__ v2W, const float* __restrict__ v2b,
    float* __restrict__ out) {
  int t = threadIdx.x;
  float a = 0.f;
#pragma unroll
  for (int g = 0; g < 32; ++g) a += vpart[g*HDIM + t];
  a = fmaxf(a + v1b[t], 0.f);
  float pv = a * v2W[t];
#pragma unroll
  for (int off = 1; off < 64; off <<= 1) pv += __shfl_xor(pv, off);
  __shared__ float wsum[4];
  if ((t & 63) == 0) wsum[t >> 6] = pv;
  __syncthreads();
  if (t == 0) out[0] = wsum[0] + wsum[1] + wsum[2] + wsum[3] + v2b[0];
}

// ---------------- host orchestration ----------------
extern "C" void kernel_launch(void* const* d_in, const int* in_sizes, int n_in,
                              void* d_out, int out_size, void* d_ws, size_t ws_size,
                              hipStream_t stream) {
  const float* x    = (const float*)d_in[0];
  const int*   ei   = (const int*)  d_in[1];
  const float* ea   = (const float*)d_in[2];
  const float* embW = (const float*)d_in[3];
  const float* embb = (const float*)d_in[4];
  const float* Wl   = (const float*)d_in[5];
  const float* bl   = (const float*)d_in[6];
  const float* Wr   = (const float*)d_in[7];
  const float* br   = (const float*)d_in[8];
  const float* We   = (const float*)d_in[9];
  const float* att  = (const float*)d_in[10];
  const float* gb   = (const float*)d_in[11];
  const float* lng  = (const float*)d_in[12];
  const float* lnb  = (const float*)d_in[13];
  const float* p1W  = (const float*)d_in[14];
  const float* p1b  = (const float*)d_in[15];
  const float* p2W  = (const float*)d_in[16];
  const float* p2b  = (const float*)d_in[17];
  const float* p3W  = (const float*)d_in[18];
  const float* p3b  = (const float*)d_in[19];
  const float* v1W  = (const float*)d_in[20];
  const float* v1b  = (const float*)d_in[21];
  const float* v2W  = (const float*)d_in[22];
  const float* v2b  = (const float*)d_in[23];
  const float* coup = (const float*)d_in[24];

  int N = in_sizes[0];         // 512
  int E = in_sizes[2] / 3;     // 260000
  float* out = (float*)d_out;
  size_t P = (size_t)N*(N-1)/2;

  // ---- workspace carve ----
  char* w = (char*)d_ws;
  int*    rcnt = (int*)   (w + 0);         // 2048 (zeroed)
  float*  asum = (float*) (w + 2048);      // 6144 (zeroed)
  int*    dcol = (int*)   (w + 8192);      // 4096 (zeroed) -> 12288
  float*  epart= (float*) (w + 12288);     // 8 -> 12544
  float*  ul   = (float*) (w + 12544);     // 1024
  float*  vl   = (float*) (w + 13568);     // 1024
  float*  ur   = (float*) (w + 14592);     // 1024
  float*  vr   = (float*) (w + 15616);     // 1024 -> 16640
  float*  psums= (float*) (w + 16640);     // 32768 -> 49408
  float*  pmaxs= (float*) (w + 49408);     // 32768 -> 82176
  float*  vprt = (float*) (w + 82176);     // 32768 -> 114944
  float4* csr  = (float4*)(w + 114944);    // 512*768*16 = 6291456 -> 6406400
  float*  hA   = (float*) (w + 6406400);   // 524288 -> 6930688
  float*  hB   = (float*) (w + 6930688);   // 524288 -> 7454976
  float*  h3   = (float*) (w + 7454976);   // 524288 -> 7979264
  unsigned short* xlh0 = (unsigned short*)(w + 7979264);  // 262144 -> 8241408
  unsigned short* xrh0 = (unsigned short*)(w + 8241408);  // 262144 -> 8503552
  unsigned short* xlh1 = (unsigned short*)(w + 8503552);  // 262144 -> 8765696
  unsigned short* xrh1 = (unsigned short*)(w + 8765696);  // 262144 -> 9027840
  unsigned short* xlh2 = (unsigned short*)(w + 9027840);  // 262144 -> 9289984
  unsigned short* xrh2 = (unsigned short*)(w + 9289984);  // 262144 -> 9552128
  unsigned short* Abh  = (unsigned short*)(w + 9552128);  // 262144 -> 9814272
  unsigned short* Bbh  = (unsigned short*)(w + 9814272);  // 262144 -> 10076416
  unsigned short* W2h  = (unsigned short*)(w + 10076416); // 65536 -> 10141952
  unsigned short* Whall= (unsigned short*)(w + 10141952); // 1310720 -> 11452672

  int WB = (E + 1023) >> 10;

  zero_k<<<12, 256, 0, stream>>>((int*)w);           // rcnt+asum+dcol
  prep_k<<<WB + 672 + 2, 256, 0, stream>>>(
      ei, ea, E, Wl, Wr, p1W, p2W, embW, embb, bl, br,
      rcnt, asum, dcol, csr, Whall, W2h, ul, vl, ur, vr);

  // layer 0: gather from rank-1 maps, then GEMM for layer 1 (Wl[1], Wr[1])
  gm0_k<<<N, 256, 0, stream>>>(
      x, embW, embb, ul, vl, ur, vr, csr, rcnt, asum, dcol,
      We, att, gb, lng, lnb,
      Whall + (size_t)1*65536, Whall + (size_t)5*65536,
      bl + HDIM, br + HDIM,
      hA, xlh0, xrh0, epart, N);

  // layer 1 (gemm -> layer 2), finalizes energy
  gm_k<<<N, 256, 0, stream>>>(
      xlh0, xrh0, hA, csr, rcnt, asum,
      We + (size_t)1*3*HDIM, att + (size_t)1*HDIM,
      gb + HDIM, lng + HDIM, lnb + HDIM,
      Whall + (size_t)2*65536, Whall + (size_t)6*65536,
      bl + 2*HDIM, br + 2*HDIM,
      hB, xlh1, xrh1, epart, coup, out + P + 1, N);

  // layer 2 (gemm -> layer 3)
  gm_k<<<N, 256, 0, stream>>>(
      xlh1, xrh1, hB, csr, rcnt, asum,
      We + (size_t)2*3*HDIM, att + (size_t)2*HDIM,
      gb + 2*HDIM, lng + 2*HDIM, lnb + 2*HDIM,
      Whall + (size_t)3*65536, Whall + (size_t)7*65536,
      bl + 3*HDIM, br + 3*HDIM,
      hA, xlh2, xrh2, epart, coup, (float*)nullptr, N);

  // layer 3 (gemm -> pair head A/B)
  gm_k<<<N, 256, 0, stream>>>(
      xlh2, xrh2, hA, csr, rcnt, asum,
      We + (size_t)3*3*HDIM, att + (size_t)3*HDIM,
      gb + 3*HDIM, lng + 3*HDIM, lnb + 3*HDIM,
      Whall + (size_t)8*65536, Whall + (size_t)9*65536,
      p1b, (const float*)nullptr,
      h3, Abh, Bbh, epart, coup, (float*)nullptr, N);

  pair_mfma_kernel<<<1056, 256, 0, stream>>>(Abh, Bbh, W2h, p2b, p3W, p3b, out, N);

  pool_kernel<<<32, 256, 0, stream>>>(h3, psums, pmaxs);
  value1_kernel<<<32, 256, 0, stream>>>(psums, pmaxs, v1W, vprt, N);
  value2_kernel<<<1, 256, 0, stream>>>(vprt, v1b, v2W, v2b, out + P);
}